// Round 4
// baseline (95.513 us; speedup 1.0000x reference)
//
#include <hip/hip_runtime.h>

#define T_ 4
#define B_ 8
#define C_ 256
#define TB_ 32
#define SQRT2_ 1.4142135623730951
#define INVS2_ 0.7071067811865475
#define EPS_ 1e-5

typedef __attribute__((ext_vector_type(8))) short short8;
typedef __attribute__((ext_vector_type(4))) float f32x4;

// ---- workspace layout ----
#define XS_OFF   ((size_t)0)           // u8 xs (T,B,C,32,32)   8 MB
#define H1C_OFF  ((size_t)8388608)     // i8 h1 codes           8 MB
#define COEF_OFF ((size_t)16777216)    // bf16 coefL dumps     16 MB (512 blocks x 32KB)
#define ST_OFF   ((size_t)33554432)    // doubles stats
// stats (double indices)
#define S1S 0
#define S1Q 512
#define S2S 1024
#define S2Q 2048
#define S3S 3072
#define S3Q 3328
#define S4S 3584
#define S4Q 3840
#define S5S 4096
#define S5Q 4352
#define NST 4608

__device__ __forceinline__ unsigned short f2bf(float v) {
    union { float f; unsigned u; } x; x.f = v;
    unsigned r = x.u + 0x7FFFu + ((x.u >> 16) & 1u);
    return (unsigned short)(r >> 16);
}

// BN1 params (channel ch in [0,512)); A includes *INVS2 (value = code*A + B)
__device__ __forceinline__ void bn1p(const double* __restrict__ st, int ch,
                                     const float* __restrict__ g, const float* __restrict__ bb,
                                     double& A, double& Bv) {
    const double sum = st[S1S + ch] * INVS2_;
    const double sq  = st[S1Q + ch] * 0.5;
    const double m = sum / 16384.0;
    const double var = sq / 16384.0 - m * m;
    const double a = (double)g[ch] / sqrt(var + EPS_);
    A = a * INVS2_;
    Bv = (double)bb[ch] - m * a;
}

// BN2 params + channel energy gate (ch in [0,1024))
__device__ __forceinline__ void bn2p(const double* __restrict__ st, int ch,
                                     const float* __restrict__ g, const float* __restrict__ bb,
                                     float& A, float& Bv) {
    const double sum = st[S2S + ch], sq = st[S2Q + ch];
    const double e = sq / 8192.0;
    const double tau = (ch < 256) ? 0.01 : (ch < 768 ? 0.02 : 0.05);
    if (e - tau >= 0.0) {
        const double m = sum / 8192.0;
        const double var = sq / 8192.0 - m * m;
        const double a = (double)g[ch] / sqrt(var + EPS_);
        A = (float)a; Bv = (float)((double)bb[ch] - m * a);
    } else { A = 0.0f; Bv = bb[ch]; }
}

// ============ K1: LIF (fp64) -> xs(u8), h1c(i8) + BN1 stats ============
__global__ __launch_bounds__(256) void k1_lif(const float* __restrict__ x,
                                              unsigned char* __restrict__ xs,
                                              signed char* __restrict__ h1c,
                                              double* __restrict__ st) {
    const int b = blockIdx.x >> 6, cg = blockIdx.x & 63;
    const int tid = threadIdx.x, wid = tid >> 6, lane = tid & 63;
    const int c = cg * 4 + wid;
    const int h = lane >> 1, wseg = (lane & 1) * 16;
    double v[16];
    #pragma unroll
    for (int i = 0; i < 16; ++i) v[i] = 0.0;
    int slo = 0, slo2 = 0, shi = 0, shi2 = 0;
    for (int t = 0; t < T_; ++t) {
        const size_t xi = ((size_t)((t * 8 + b) * 256 + c)) * 1024 + h * 32 + wseg;
        const float4* xp = (const float4*)(x + xi);
        unsigned spk[4], lo8[2], hi8[2];
        #pragma unroll
        for (int q4 = 0; q4 < 4; ++q4) {
            const float4 xv = xp[q4];
            int sp[4];
            #pragma unroll
            for (int e = 0; e < 4; ++e) {
                const double xd = (e == 0 ? xv.x : e == 1 ? xv.y : e == 2 ? xv.z : xv.w);
                double vv = v[q4 * 4 + e];
                vv = vv + (xd - vv) * 0.5;
                const int s = (vv - 1.0 >= 0.0) ? 1 : 0;
                if (s) vv = 0.0;
                v[q4 * 4 + e] = vv;
                sp[e] = s;
            }
            spk[q4] = (unsigned)(sp[0] | (sp[1] << 8) | (sp[2] << 16) | (sp[3] << 24));
            const int lo0 = sp[0] + sp[1], lo1 = sp[2] + sp[3];
            const int hi0 = sp[0] - sp[1], hi1 = sp[2] - sp[3];
            slo += lo0 + lo1; slo2 += lo0 * lo0 + lo1 * lo1;
            shi += hi0 + hi1; shi2 += hi0 * hi0 + hi1 * hi1;
            const unsigned lb = (unsigned)((lo0 & 0xFF) | ((lo1 & 0xFF) << 8));
            const unsigned hb = (unsigned)((hi0 & 0xFF) | ((hi1 & 0xFF) << 8));
            if (q4 == 0) { lo8[0] = lb; hi8[0] = hb; }
            else if (q4 == 1) { lo8[0] |= lb << 16; hi8[0] |= hb << 16; }
            else if (q4 == 2) { lo8[1] = lb; hi8[1] = hb; }
            else { lo8[1] |= lb << 16; hi8[1] |= hb << 16; }
        }
        *(uint4*)(xs + xi) = make_uint4(spk[0], spk[1], spk[2], spk[3]);
        const size_t lob = ((size_t)((t * 8 + b) * 512 + c)) * 512 + h * 16 + (lane & 1) * 8;
        const size_t hib = ((size_t)((t * 8 + b) * 512 + 256 + c)) * 512 + h * 16 + (lane & 1) * 8;
        *(uint2*)(h1c + lob) = make_uint2(lo8[0], lo8[1]);
        *(uint2*)(h1c + hib) = make_uint2(hi8[0], hi8[1]);
    }
    int vals[4] = {slo, slo2, shi, shi2};
    #pragma unroll
    for (int k = 0; k < 4; ++k)
        #pragma unroll
        for (int m = 1; m < 64; m <<= 1) vals[k] += __shfl_xor(vals[k], m, 64);
    if (lane == 0) {
        atomicAdd(&st[S1S + c], (double)vals[0]);
        atomicAdd(&st[S1Q + c], (double)vals[1]);
        atomicAdd(&st[S1S + 256 + c], (double)vals[2]);
        atomicAdd(&st[S1Q + 256 + c], (double)vals[3]);
    }
}

// ============ K4s: BN2/energy stats from h1c ============
__global__ __launch_bounds__(256) void k4s(const signed char* __restrict__ h1c,
                                           double* __restrict__ st,
                                           const float* __restrict__ g_fwd,
                                           const float* __restrict__ b_fwd) {
    const int tb = blockIdx.x >> 6, cg = blockIdx.x & 63;
    const int tid = threadIdx.x, wid = tid >> 6, lane = tid & 63;
    const int c = cg * 4 + wid;
    __shared__ double A1s[8], B1s[8];
    if (tid < 8) {
        const int cl = cg * 4 + (tid & 3), band = tid >> 2;
        double A, Bv; bn1p(st, band * 256 + cl, g_fwd, b_fwd, A, Bv);
        A1s[tid] = A; B1s[tid] = Bv;
    }
    __syncthreads();
    const double Alo = A1s[wid], Blo = B1s[wid];
    const double Ahi = A1s[4 + wid], Bhi = B1s[4 + wid];
    const int h2 = lane >> 2, w2b = (lane & 3) * 4;
    const size_t lob = ((size_t)(tb * 512 + c)) * 512 + (2 * h2) * 16 + w2b;
    const size_t hib = ((size_t)(tb * 512 + 256 + c)) * 512 + (2 * h2) * 16 + w2b;
    const unsigned la = *(const unsigned*)(h1c + lob);
    const unsigned lb = *(const unsigned*)(h1c + lob + 16);
    const unsigned qa = *(const unsigned*)(h1c + hib);
    const unsigned qb = *(const unsigned*)(h1c + hib + 16);
    double acc[8] = {0, 0, 0, 0, 0, 0, 0, 0};
    #pragma unroll
    for (int m = 0; m < 4; ++m) {
        const int l0 = (int)(signed char)(la >> (8 * m));
        const int l1 = (int)(signed char)(lb >> (8 * m));
        const int q0 = (int)(signed char)(qa >> (8 * m));
        const int q1 = (int)(signed char)(qb >> (8 * m));
        const double L0 = (double)l0 * Alo + Blo;
        const double L1 = (double)l1 * Alo + Blo;
        const double Q0 = (double)q0 * Ahi + Bhi;
        const double Q1 = (double)q1 * Ahi + Bhi;
        double LL = (L0 + L1) * INVS2_, HL = (L0 - L1) * INVS2_;
        double LH = (Q0 + Q1) * INVS2_, HH = (Q0 - Q1) * INVS2_;
        LL = (fabs(LL) - 0.5 >= 0.0) ? LL : 0.0;
        HL = (fabs(HL) - 0.5 >= 0.0) ? HL : 0.0;
        LH = (fabs(LH) - 0.5 >= 0.0) ? LH : 0.0;
        HH = (fabs(HH) - 0.5 >= 0.0) ? HH : 0.0;
        acc[0] += LL; acc[1] += LL * LL;
        acc[2] += HL; acc[3] += HL * HL;
        acc[4] += LH; acc[5] += LH * LH;
        acc[6] += HH; acc[7] += HH * HH;
    }
    #pragma unroll
    for (int k = 0; k < 8; ++k)
        #pragma unroll
        for (int m = 1; m < 64; m <<= 1) acc[k] += __shfl_xor(acc[k], m, 64);
    if (lane == 0) {
        #pragma unroll
        for (int q = 0; q < 4; ++q) {
            atomicAdd(&st[S2S + q * 256 + c], acc[2 * q]);
            atomicAdd(&st[S2Q + q * 256 + c], acc[2 * q + 1]);
        }
    }
}

// ---- copy 8 KB global->LDS with coalesced uint4 ----
__device__ __forceinline__ void stage8k(const char* __restrict__ src, char* dst, int tid) {
    *(uint4*)(dst + tid * 16) = *(const uint4*)(src + tid * 16);
    *(uint4*)(dst + 4096 + tid * 16) = *(const uint4*)(src + 4096 + tid * 16);
}

// ---- coef build from LDS-staged raw h1c codes ----
// rawL: [band(2)][d(16)][pos(512)] i8.  Output coefL: [pair(2)][P(256)][kk(32)] bf16,
// 16B-slot swizzled: slot ^= P&3.
__device__ __forceinline__ void coef_build(const signed char* rawL, int tid,
                                           const double* A1L, const double* B1L,
                                           const float* A2L, const float* B2L,
                                           unsigned short* coefL) {
    const int h2 = tid >> 4, w2 = tid & 15;
    const int P = tid;
    unsigned pk[4][8];
    #pragma unroll
    for (int d = 0; d < 16; ++d) {
        const int base = d * 512 + h2 * 32 + w2;
        const int l0 = rawL[base], l1 = rawL[base + 16];
        const int q0 = rawL[8192 + base], q1 = rawL[8192 + base + 16];
        const double Alo = A1L[d], Blo = B1L[d];
        const double Ahi = A1L[16 + d], Bhi = B1L[16 + d];
        const double L0 = (double)l0 * Alo + Blo;
        const double L1 = (double)l1 * Alo + Blo;
        const double Q0 = (double)q0 * Ahi + Bhi;
        const double Q1 = (double)q1 * Ahi + Bhi;
        double LL = (L0 + L1) * INVS2_, HL = (L0 - L1) * INVS2_;
        double LH = (Q0 + Q1) * INVS2_, HH = (Q0 - Q1) * INVS2_;
        LL = (fabs(LL) - 0.5 >= 0.0) ? LL : 0.0;
        HL = (fabs(HL) - 0.5 >= 0.0) ? HL : 0.0;
        LH = (fabs(LH) - 0.5 >= 0.0) ? LH : 0.0;
        HH = (fabs(HH) - 0.5 >= 0.0) ? HH : 0.0;
        const float vq0 = fmaf((float)LL, A2L[d],      B2L[d]);
        const float vq1 = fmaf((float)HL, A2L[16 + d], B2L[16 + d]);
        const float vq2 = fmaf((float)LH, A2L[32 + d], B2L[32 + d]);
        const float vq3 = fmaf((float)HH, A2L[48 + d], B2L[48 + d]);
        const unsigned h0 = f2bf(vq0), h1v = f2bf(vq1), h2v = f2bf(vq2), h3 = f2bf(vq3);
        if (d & 1) {
            pk[0][d >> 1] |= h0 << 16; pk[1][d >> 1] |= h1v << 16;
            pk[2][d >> 1] |= h2v << 16; pk[3][d >> 1] |= h3 << 16;
        } else {
            pk[0][d >> 1] = h0; pk[1][d >> 1] = h1v;
            pk[2][d >> 1] = h2v; pk[3][d >> 1] = h3;
        }
    }
    #pragma unroll
    for (int q = 0; q < 4; ++q) {
        const int pair = q >> 1;
        #pragma unroll
        for (int db = 0; db < 2; ++db) {
            const int slot = (((q & 1) * 2 + db) ^ (P & 3));
            char* dst = (char*)coefL + pair * 16384 + P * 64 + slot * 16;
            *(uint4*)dst = make_uint4(pk[q][db * 4], pk[q][db * 4 + 1], pk[q][db * 4 + 2], pk[q][db * 4 + 3]);
        }
    }
}

// ---- mix A-fragments: half-zeroed haar weights per quadrant ----
__device__ __forceinline__ void mix_frags(const float* __restrict__ hw, int gb, int lane, short8 am[4]) {
    const int o = lane & 15, g = lane >> 4;
    #pragma unroll
    for (int q = 0; q < 4; ++q) {
        #pragma unroll
        for (int e = 0; e < 8; ++e) {
            const int kk = g * 8 + e;
            unsigned short v = 0;
            if ((kk >> 4) == (q & 1)) {
                const int d = kk & 15;
                const int nbp = q * 4 + (gb >> 2);
                v = f2bf(hw[(nbp * 16 + d) * 16 + o]);
            }
            am[q][e] = (short)v;
        }
    }
}

// ---- mix one h2-row: 2 ds_read + 4 MFMA ----
__device__ __forceinline__ void mix_hh(const unsigned short* coefL, const short8 am[4],
                                       int lane, int wid, int hh, f32x4 Mh[4]) {
    const int o = lane & 15, g = lane >> 4;
    const int P = (wid * 4 + hh) * 16 + o;
    #pragma unroll
    for (int p = 0; p < 2; ++p) {
        const int slot = g ^ (P & 3);
        const short8 bf = *(const short8*)((const char*)coefL + p * 16384 + P * 64 + slot * 16);
        const f32x4 z = {0.f, 0.f, 0.f, 0.f};
        Mh[2 * p]     = __builtin_amdgcn_mfma_f32_16x16x32_bf16(am[2 * p], bf, z, 0, 0, 0);
        Mh[2 * p + 1] = __builtin_amdgcn_mfma_f32_16x16x32_bf16(am[2 * p + 1], bf, z, 0, 0, 0);
    }
}

// ---- conv tile build from LDS-staged raw xs: tile[34][34][16] bf16, (c&4)<<2 swizzle ----
__device__ __forceinline__ void tile_build(const unsigned char* rawX, int tid, unsigned short* tile) {
    for (int it = 0; it < 5; ++it) {
        const int idx = tid + it * 256;
        if (idx < 34 * 34) {
            const int r = idx / 34, c = idx % 34;
            const int gh = r - 1, gw = c - 1;
            unsigned v[8] = {0u, 0u, 0u, 0u, 0u, 0u, 0u, 0u};
            if (((unsigned)gh < 32u) & ((unsigned)gw < 32u)) {
                const int p = gh * 32 + gw;
                #pragma unroll
                for (int dp = 0; dp < 8; ++dp) {
                    const unsigned b0 = rawX[2 * dp * 1024 + p];
                    const unsigned b1 = rawX[(2 * dp + 1) * 1024 + p];
                    v[dp] = (b0 | (b1 << 16)) * 0x3F80u;
                }
            }
            const int base = (r * 34 + c) * 32;
            const int sw = (c & 4) << 2;
            *(uint4*)((char*)tile + (base ^ sw)) = make_uint4(v[0], v[1], v[2], v[3]);
            *(uint4*)((char*)tile + ((base + 16) ^ sw)) = make_uint4(v[4], v[5], v[6], v[7]);
        }
    }
}

__device__ __forceinline__ void conv_frags(const float* __restrict__ w1, const float* __restrict__ w2w,
                                           int lane, short8* awc2, short8& awc1) {
    const int o = lane & 15, g = lane >> 4, dA = (g & 1) * 8;
    #pragma unroll
    for (int m = 0; m < 5; ++m) {
        const int t = (m < 4) ? (2 * m + (g >> 1)) : 8;
        const bool act = (m < 4) || (g < 2);
        #pragma unroll
        for (int j = 0; j < 8; ++j) {
            const float wv = act ? w2w[(o * 16 + dA + j) * 9 + t] : 0.0f;
            awc2[m][j] = (short)f2bf(wv);
        }
    }
    #pragma unroll
    for (int j = 0; j < 8; ++j) {
        const float wv = (g < 2) ? w1[o * 16 + dA + j] : 0.0f;
        awc1[j] = (short)f2bf(wv);
    }
}

__device__ __forceinline__ void conv_tile(const unsigned short* tile, int lane, int h, int w0,
                                          const short8* awc2, const short8& awc1,
                                          f32x4& acc2o, f32x4& acc1o) {
    const int g = lane >> 4, n = lane & 15, dA = (g & 1) * 8;
    short8 bf[6];
    #pragma unroll
    for (int m = 0; m < 6; ++m) {
        const int t = (m < 4) ? (2 * m + (g >> 1)) : ((m == 4) ? 8 : 4);
        const int ky = t / 3, kx = t % 3;
        const int rr = h + ky, cc = w0 + n + kx;
        const int addr = (((rr * 34 + cc) * 32) + dA * 2) ^ ((cc & 4) << 2);
        bf[m] = *(const short8*)((const char*)tile + addr);
    }
    f32x4 acc2 = {0.f, 0.f, 0.f, 0.f};
    #pragma unroll
    for (int m = 0; m < 5; ++m)
        acc2 = __builtin_amdgcn_mfma_f32_16x16x32_bf16(awc2[m], bf[m], acc2, 0, 0, 0);
    const f32x4 z = {0.f, 0.f, 0.f, 0.f};
    acc1o = __builtin_amdgcn_mfma_f32_16x16x32_bf16(awc1, bf[5], z, 0, 0, 0);
    acc2o = acc2;
}

// ============ KMID: [0,512): BN3 stats via mix-MFMA (+ coef dump); [512,1024): conv stats ============
__global__ __launch_bounds__(256) void kmid(const unsigned char* __restrict__ xs,
                                            const signed char* __restrict__ h1c,
                                            double* __restrict__ st,
                                            char* __restrict__ coefD,
                                            const float* __restrict__ haar_w,
                                            const float* __restrict__ g_fwd, const float* __restrict__ b_fwd,
                                            const float* __restrict__ g_mul, const float* __restrict__ b_mul,
                                            const float* __restrict__ conv1_w, const float* __restrict__ conv2_w) {
    __shared__ __align__(16) char smem[53376];
    const int tid = threadIdx.x, lane = tid & 63, wid = tid >> 6;
    if (blockIdx.x < 512) {
        const int tb = blockIdx.x >> 4, gb = blockIdx.x & 15;
        double* A1L = (double*)smem;
        double* B1L = (double*)(smem + 256);
        float* A2L = (float*)(smem + 512);
        float* B2L = (float*)(smem + 768);
        float* padd = (float*)(smem + 1024);               // [4][16][2]
        unsigned short* coefL = (unsigned short*)(smem + 1536);
        signed char* rawL = (signed char*)(smem + 34304);  // 16 KB
        if (tid < 32) {
            const int d = tid & 15, band = tid >> 4;
            double A, Bv; bn1p(st, band * 256 + gb * 16 + d, g_fwd, b_fwd, A, Bv);
            A1L[tid] = A; B1L[tid] = Bv;
        } else if (tid < 96) {
            const int k = tid - 32, q = k >> 4, d = k & 15;
            float A, Bv; bn2p(st, q * 256 + gb * 16 + d, g_mul, b_mul, A, Bv);
            A2L[k] = A; B2L[k] = Bv;
        }
        stage8k((const char*)(h1c + ((size_t)(tb * 512 + gb * 16)) * 512), (char*)rawL, tid);
        stage8k((const char*)(h1c + ((size_t)(tb * 512 + 256 + gb * 16)) * 512), (char*)rawL + 8192, tid);
        __syncthreads();
        coef_build(rawL, tid, A1L, B1L, A2L, B2L, coefL);
        short8 am[4];
        mix_frags(haar_w, gb, lane, am);
        __syncthreads();
        // dump coefL image (swizzle included) for kfin reload
        {
            char* dump = coefD + ((size_t)(tb * 16 + gb)) * 32768;
            #pragma unroll
            for (int i = 0; i < 8; ++i)
                *(uint4*)(dump + i * 4096 + tid * 16) = *(const uint4*)((const char*)coefL + i * 4096 + tid * 16);
        }
        float s2x[4] = {0, 0, 0, 0}, se[4] = {0, 0, 0, 0};
        #pragma unroll
        for (int hh = 0; hh < 4; ++hh) {
            f32x4 Mh[4];
            mix_hh(coefL, am, lane, wid, hh, Mh);
            #pragma unroll
            for (int r = 0; r < 4; ++r) {
                s2x[r] += 2.0f * Mh[0][r];
                #pragma unroll
                for (int q = 0; q < 4; ++q) se[r] += Mh[q][r] * Mh[q][r];
            }
        }
        #pragma unroll
        for (int r = 0; r < 4; ++r)
            #pragma unroll
            for (int m = 1; m < 16; m <<= 1) {
                s2x[r] += __shfl_xor(s2x[r], m, 64);
                se[r]  += __shfl_xor(se[r], m, 64);
            }
        const int G = lane >> 4;
        if ((lane & 15) == 0) {
            #pragma unroll
            for (int r = 0; r < 4; ++r) {
                padd[(wid * 16 + G * 4 + r) * 2]     = s2x[r];
                padd[(wid * 16 + G * 4 + r) * 2 + 1] = se[r];
            }
        }
        __syncthreads();
        if (tid < 32) {
            const int j = tid >> 1, s = tid & 1;
            const float tot = padd[(0 * 16 + j) * 2 + s] + padd[(1 * 16 + j) * 2 + s]
                            + padd[(2 * 16 + j) * 2 + s] + padd[(3 * 16 + j) * 2 + s];
            atomicAdd(&st[(s ? S3Q : S3S) + gb * 16 + j], (double)tot);
        }
    } else {
        const int bid = blockIdx.x - 512;
        const int tb = bid >> 4, gb = bid & 15;
        unsigned char* rawX = (unsigned char*)smem;            // 16 KB
        unsigned short* tile = (unsigned short*)(smem + 16384); // 36992
        const char* src = (const char*)(xs + (size_t)(tb * 256 + gb * 16) * 1024);
        stage8k(src, (char*)rawX, tid);
        stage8k(src + 8192, (char*)rawX + 8192, tid);
        short8 awc2[5], awc1;
        conv_frags(conv1_w, conv2_w, lane, awc2, awc1);
        __syncthreads();
        tile_build(rawX, tid, tile);
        __syncthreads();
        double t1s[4] = {0, 0, 0, 0}, t1q[4] = {0, 0, 0, 0};
        double t2s[4] = {0, 0, 0, 0}, t2q[4] = {0, 0, 0, 0};
        for (int ti = 0; ti < 16; ++ti) {
            const int h = wid * 8 + (ti >> 1), w0 = (ti & 1) * 16;
            f32x4 a2v, a1v;
            conv_tile(tile, lane, h, w0, awc2, awc1, a2v, a1v);
            #pragma unroll
            for (int r = 0; r < 4; ++r) {
                t1s[r] += a1v[r]; t1q[r] += (double)a1v[r] * a1v[r];
                t2s[r] += a2v[r]; t2q[r] += (double)a2v[r] * a2v[r];
            }
        }
        #pragma unroll
        for (int r = 0; r < 4; ++r)
            #pragma unroll
            for (int m = 1; m < 16; m <<= 1) {
                t1s[r] += __shfl_xor(t1s[r], m, 64);
                t1q[r] += __shfl_xor(t1q[r], m, 64);
                t2s[r] += __shfl_xor(t2s[r], m, 64);
                t2q[r] += __shfl_xor(t2q[r], m, 64);
            }
        if ((lane & 15) == 0) {
            const int G = lane >> 4;
            #pragma unroll
            for (int r = 0; r < 4; ++r) {
                const int ch = gb * 16 + G * 4 + r;
                atomicAdd(&st[S4S + ch], t1s[r]);
                atomicAdd(&st[S4Q + ch], t1q[r]);
                atomicAdd(&st[S5S + ch], t2s[r]);
                atomicAdd(&st[S5Q + ch], t2q[r]);
            }
        }
    }
}

// ============ KFIN: reload coef + rebuild tile + mix/inv-Haar/convs + BN epilogue -> out ============
__global__ __launch_bounds__(256) void kfin(const unsigned char* __restrict__ xs,
                                            const char* __restrict__ coefD,
                                            const double* __restrict__ st,
                                            const float* __restrict__ haar_w,
                                            const float* __restrict__ g_inv, const float* __restrict__ b_inv,
                                            const float* __restrict__ g_c1, const float* __restrict__ b_c1,
                                            const float* __restrict__ g_c2, const float* __restrict__ b_c2,
                                            const float* __restrict__ conv1_w, const float* __restrict__ conv1_b,
                                            const float* __restrict__ conv2_w, const float* __restrict__ conv2_b,
                                            float* __restrict__ out) {
    __shared__ __align__(16) char smem[70016];
    const int tid = threadIdx.x, lane = tid & 63, wid = tid >> 6;
    const int tb = blockIdx.x >> 4, gb = blockIdx.x & 15;
    unsigned short* tile  = (unsigned short*)smem;            // 36992
    unsigned short* coefL = (unsigned short*)(smem + 36992);  // 32768
    float* PA3 = (float*)(smem + 69760);
    float* PA4 = PA3 + 16; float* PA5 = PA3 + 32; float* PK = PA3 + 48;
    if (tid < 16) {
        const int oc = tid, c = gb * 16 + oc;
        const double n3 = 32768.0;
        const double m3 = st[S3S + c] / n3, var3 = st[S3Q + c] / n3 - m3 * m3;
        const double a3 = (double)g_inv[c] / sqrt(var3 + EPS_);
        const double bias1 = (double)conv1_b[oc];
        const double s4 = st[S4S + c] + n3 * bias1;
        const double q4v = st[S4Q + c] + 2.0 * bias1 * st[S4S + c] + n3 * bias1 * bias1;
        const double m4 = s4 / n3, var4 = q4v / n3 - m4 * m4;
        const double a4 = (double)g_c1[c] / sqrt(var4 + EPS_);
        const double bias2 = (double)conv2_b[oc];
        const double s5 = st[S5S + c] + n3 * bias2;
        const double q5v = st[S5Q + c] + 2.0 * bias2 * st[S5S + c] + n3 * bias2 * bias2;
        const double m5 = s5 / n3, var5 = q5v / n3 - m5 * m5;
        const double a5 = (double)g_c2[c] / sqrt(var5 + EPS_);
        PA3[oc] = (float)a3; PA4[oc] = (float)a4; PA5[oc] = (float)a5;
        PK[oc] = (float)(((double)b_inv[c] - m3 * a3) + ((double)b_c1[c] - m4 * a4)
                       + ((double)b_c2[c] - m5 * a5) + a4 * bias1 + a5 * bias2);
    }
    // stage raw xs into (not-yet-needed) coefL region, build tile, then reload coef over it
    {
        unsigned char* rawX = (unsigned char*)coefL;
        const char* src = (const char*)(xs + (size_t)(tb * 256 + gb * 16) * 1024);
        stage8k(src, (char*)rawX, tid);
        stage8k(src + 8192, (char*)rawX + 8192, tid);
        __syncthreads();
        tile_build(rawX, tid, tile);
        __syncthreads();
        const char* dump = coefD + ((size_t)(tb * 16 + gb)) * 32768;
        #pragma unroll
        for (int i = 0; i < 8; ++i)
            *(uint4*)((char*)coefL + i * 4096 + tid * 16) = *(const uint4*)(dump + i * 4096 + tid * 16);
    }
    short8 am[4], awc2[5], awc1;
    mix_frags(haar_w, gb, lane, am);
    conv_frags(conv1_w, conv2_w, lane, awc2, awc1);
    __syncthreads();
    const int G = lane >> 4, n = lane & 15;
    float fA3[4], fA4[4], fA5[4], fK[4];
    #pragma unroll
    for (int r = 0; r < 4; ++r) {
        const int oc = G * 4 + r;
        fA3[r] = PA3[oc]; fA4[r] = PA4[oc]; fA5[r] = PA5[oc]; fK[r] = PK[oc];
    }
    const float sw = (n & 1) ? -1.0f : 1.0f;
    #pragma unroll
    for (int hh = 0; hh < 4; ++hh) {
        f32x4 Mh[4];
        mix_hh(coefL, am, lane, wid, hh, Mh);
        #pragma unroll
        for (int w0h = 0; w0h < 2; ++w0h) {
            const int src = (lane & 48) + w0h * 8 + (n >> 1);
            float ms[4][4];
            #pragma unroll
            for (int q = 0; q < 4; ++q)
                #pragma unroll
                for (int r = 0; r < 4; ++r) ms[q][r] = __shfl(Mh[q][r], src, 64);
            #pragma unroll
            for (int hrow = 0; hrow < 2; ++hrow) {
                const float sh = hrow ? -1.0f : 1.0f;
                const int h = wid * 8 + hh * 2 + hrow;
                const int w0 = w0h * 16;
                f32x4 a2v, a1v;
                conv_tile(tile, lane, h, w0, awc2, awc1, a2v, a1v);
                #pragma unroll
                for (int r = 0; r < 4; ++r) {
                    const float rec = 0.5f * ((ms[0][r] + sh * ms[1][r]) + sw * (ms[2][r] + sh * ms[3][r]));
                    const int oc = G * 4 + r;
                    const size_t ai = ((size_t)(tb * 256 + gb * 16 + oc)) * 1024 + (size_t)h * 32 + w0 + n;
                    out[ai] = fA3[r] * rec + fA4[r] * a1v[r] + fA5[r] * a2v[r] + fK[r];
                }
            }
        }
    }
}

extern "C" void kernel_launch(void* const* d_in, const int* in_sizes, int n_in,
                              void* d_out, int out_size, void* d_ws, size_t ws_size,
                              hipStream_t stream) {
    const float* x        = (const float*)d_in[0];
    const float* haar_w   = (const float*)d_in[1];
    const float* conv1_w  = (const float*)d_in[2];
    const float* conv1_b  = (const float*)d_in[3];
    const float* conv2_w  = (const float*)d_in[4];
    const float* conv2_b  = (const float*)d_in[5];
    const float* g_fwd    = (const float*)d_in[6];
    const float* b_fwd    = (const float*)d_in[7];
    const float* g_mul    = (const float*)d_in[8];
    const float* b_mul    = (const float*)d_in[9];
    const float* g_inv    = (const float*)d_in[10];
    const float* b_inv    = (const float*)d_in[11];
    const float* g_c1     = (const float*)d_in[12];
    const float* b_c1     = (const float*)d_in[13];
    const float* g_c2     = (const float*)d_in[14];
    const float* b_c2     = (const float*)d_in[15];
    float* out = (float*)d_out;

    char* ws = (char*)d_ws;
    unsigned char* xs = (unsigned char*)(ws + XS_OFF);
    signed char* h1c  = (signed char*)(ws + H1C_OFF);
    char* coefD       = ws + COEF_OFF;
    double* st        = (double*)(ws + ST_OFF);

    hipMemsetAsync(st, 0, NST * sizeof(double), stream);
    k1_lif<<<dim3(512), dim3(256), 0, stream>>>(x, xs, h1c, st);
    k4s<<<dim3(2048), dim3(256), 0, stream>>>(h1c, st, g_fwd, b_fwd);
    kmid<<<dim3(1024), dim3(256), 0, stream>>>(xs, h1c, st, coefD, haar_w, g_fwd, b_fwd,
                                               g_mul, b_mul, conv1_w, conv2_w);
    kfin<<<dim3(512), dim3(256), 0, stream>>>(xs, coefD, st, haar_w,
                                              g_inv, b_inv, g_c1, b_c1, g_c2, b_c2,
                                              conv1_w, conv1_b, conv2_w, conv2_b, out);
}